// Round 1
// baseline (11491.869 us; speedup 1.0000x reference)
//
#include <hip/hip_runtime.h>
#include <math.h>

#define Ldim 16
#define BATCH 8
#define Hdim 32
#define Wdim 32
#define Udim 128
#define Pdim 256

// workspace float offsets
#define OFF_WBR 0
#define OFF_WBI 294912
#define OFF_WCR 589824
#define OFF_WCI 884736
#define OFF_ARE 1179648
#define OFF_AIM 1179904
#define OFF_BUSR 1180160
#define OFF_BUSI 5374464
#define OFF_YS 9568768
#define OFF_STATS 11665920

// ---------------- prep: A_bar + transposed/scaled weights ----------------
__global__ __launch_bounds__(256)
void prep_kernel(const float* __restrict__ Lre, const float* __restrict__ Lim,
                 const float* __restrict__ B_ri, const float* __restrict__ C_ri,
                 const float* __restrict__ log_step, float* __restrict__ ws) {
    float* WbR = ws + OFF_WBR;
    float* WbI = ws + OFF_WBI;
    float* WcR = ws + OFF_WCR;
    float* WcI = ws + OFF_WCI;
    float* Are = ws + OFF_ARE;
    float* Aim = ws + OFF_AIM;
    int tid = blockIdx.x * blockDim.x + threadIdx.x;
    const int total = Pdim * Udim * 9;  // 294912

    if (tid < Pdim) {
        float st = expf(log_step[tid]);
        Are[tid] = fminf(Lre[tid], -1e-4f) * st;
        Aim[tid] = Lim[tid] * st;
    }

    for (int i = tid; i < total; i += gridDim.x * blockDim.x) {
        // B weights: i = (p*U + u)*9 + t
        {
            int t = i % 9;
            int pu = i / 9;
            int u = pu % Udim;
            int p = pu / Udim;
            float st = expf(log_step[p]);
            float br = B_ri[(size_t)i * 2 + 0] * st;
            float bi = B_ri[(size_t)i * 2 + 1] * st;
            WbR[(t * Udim + u) * Pdim + p] = br;
            WbI[(t * Udim + u) * Pdim + p] = bi;
        }
        // C weights: i = (u*P + p)*9 + t
        {
            int t = i % 9;
            int up = i / 9;
            int p = up % Pdim;
            int u = up / Pdim;
            float cr = C_ri[(size_t)i * 2 + 0];
            float ci = C_ri[(size_t)i * 2 + 1];
            WcR[(t * Pdim + p) * Udim + u] = cr;
            WcI[(t * Pdim + p) * Udim + u] = ci;
        }
    }
}

// ---------------- B conv: Bus = u (*) B_bar (complex out) ----------------
// grid (W/8, H, L), block 256 (= p). 8 pixels per block.
__global__ __launch_bounds__(256)
void bconv_kernel(const float* __restrict__ useq, const float* __restrict__ ws,
                  float* __restrict__ BusR, float* __restrict__ BusI, int b) {
    const float* WbR = ws + OFF_WBR;
    const float* WbI = ws + OFF_WBI;
    __shared__ float patch[3 * 10 * Udim];  // 3840 floats
    int p = threadIdx.x;
    int w0 = blockIdx.x * 8;
    int h = blockIdx.y;
    int l = blockIdx.z;
    const float* frame = useq + (size_t)(l * BATCH + b) * (Hdim * Wdim * Udim);
    for (int i = p; i < 3 * 10 * Udim; i += 256) {
        int u = i % Udim;
        int c = (i / Udim) % 10;
        int r = i / (Udim * 10);
        int hh = h + r - 1;
        int wc = w0 + c - 1;
        float v = 0.f;
        if (hh >= 0 && hh < Hdim && wc >= 0 && wc < Wdim)
            v = frame[((size_t)hh * Wdim + wc) * Udim + u];
        patch[i] = v;
    }
    __syncthreads();
    float accR[8], accI[8];
#pragma unroll
    for (int px = 0; px < 8; ++px) { accR[px] = 0.f; accI[px] = 0.f; }

    for (int t = 0; t < 9; ++t) {
        int kh = t / 3, kw = t % 3;
        const float* baseP = patch + (kh * 10 + kw) * Udim;
        const float* wr = WbR + (size_t)t * Udim * Pdim + p;
        const float* wi = WbI + (size_t)t * Udim * Pdim + p;
        for (int u = 0; u < Udim; ++u) {
            float wvr = wr[(size_t)u * Pdim];
            float wvi = wi[(size_t)u * Pdim];
#pragma unroll
            for (int px = 0; px < 8; ++px) {
                float v = baseP[px * Udim + u];
                accR[px] += v * wvr;
                accI[px] += v * wvi;
            }
        }
    }
    size_t outb = ((size_t)l * Hdim * Wdim + h * Wdim + w0) * Pdim + p;
#pragma unroll
    for (int px = 0; px < 8; ++px) {
        BusR[outb + (size_t)px * Pdim] = accR[px];
        BusI[outb + (size_t)px * Pdim] = accI[px];
    }
}

// ---------------- sequential diagonal scan over L (in-place) ----------------
// grid H*W, block 256 (= p)
__global__ __launch_bounds__(256)
void scan_kernel(const float* __restrict__ x0, const float* __restrict__ ws,
                 float* __restrict__ BusR, float* __restrict__ BusI,
                 float* __restrict__ out_xlast, int b) {
    int p = threadIdx.x;
    int hw = blockIdx.x;
    float Ar = ws[OFF_ARE + p];
    float Ai = ws[OFF_AIM + p];
    float xr = x0[((size_t)b * Hdim * Wdim + hw) * Pdim + p];
    float xi = 0.f;
    size_t base = (size_t)hw * Pdim + p;
    for (int l = 0; l < Ldim; ++l) {
        size_t idx = (size_t)l * Hdim * Wdim * Pdim + base;
        float br = BusR[idx], bi = BusI[idx];
        float nr = Ar * xr - Ai * xi + br;
        float ni = Ar * xi + Ai * xr + bi;
        xr = nr; xi = ni;
        BusR[idx] = xr; BusI[idx] = xi;
    }
    size_t o = ((size_t)b * Hdim * Wdim + hw) * Pdim + p;
    out_xlast[o * 2 + 0] = xr;
    out_xlast[o * 2 + 1] = xi;
}

// ---------------- C conv + depthwise D feedthrough ----------------
// grid (W/4, H, L), block 128 (= u). 4 pixels per block.
__global__ __launch_bounds__(128)
void cconv_kernel(const float* __restrict__ useq, const float* __restrict__ ws,
                  const float* __restrict__ BusR, const float* __restrict__ BusI,
                  const float* __restrict__ Dk, float* __restrict__ ys_pdu, int b) {
    const float* WcR = ws + OFF_WCR;
    const float* WcI = ws + OFF_WCI;
    __shared__ float pr[3 * 6 * Pdim];   // 4608 floats
    __shared__ float pi_[3 * 6 * Pdim];
    int uu = threadIdx.x;
    int w0 = blockIdx.x * 4;
    int h = blockIdx.y;
    int l = blockIdx.z;
    size_t fbase = (size_t)l * Hdim * Wdim * Pdim;
    for (int i = uu; i < 3 * 6 * Pdim; i += 128) {
        int pc = i % Pdim;
        int c = (i / Pdim) % 6;
        int r = i / (Pdim * 6);
        int hh = h + r - 1;
        int wc = w0 + c - 1;
        float vr = 0.f, vi = 0.f;
        if (hh >= 0 && hh < Hdim && wc >= 0 && wc < Wdim) {
            size_t idx = fbase + ((size_t)hh * Wdim + wc) * Pdim + pc;
            vr = BusR[idx];
            vi = BusI[idx];
        }
        pr[i] = vr;
        pi_[i] = vi;
    }
    __syncthreads();
    float acc[4];
#pragma unroll
    for (int px = 0; px < 4; ++px) acc[px] = 0.f;

    for (int t = 0; t < 9; ++t) {
        int kh = t / 3, kw = t % 3;
        const float* bR = pr + (kh * 6 + kw) * Pdim;
        const float* bI = pi_ + (kh * 6 + kw) * Pdim;
        const float* wr = WcR + (size_t)t * Pdim * Udim + uu;
        const float* wi = WcI + (size_t)t * Pdim * Udim + uu;
        for (int pc = 0; pc < Pdim; ++pc) {
            float wvr = wr[(size_t)pc * Udim];
            float wvi = wi[(size_t)pc * Udim];
#pragma unroll
            for (int px = 0; px < 4; ++px) {
                acc[px] += bR[px * Pdim + pc] * wvr - bI[px * Pdim + pc] * wvi;
            }
        }
    }
    // depthwise D conv + store
    const float* frame = useq + (size_t)(l * BATCH + b) * (Hdim * Wdim * Udim);
#pragma unroll
    for (int px = 0; px < 4; ++px) {
        int w = w0 + px;
        float du = 0.f;
        for (int t = 0; t < 9; ++t) {
            int kh = t / 3, kw = t % 3;
            int hh = h + kh - 1, wc = w + kw - 1;
            if (hh >= 0 && hh < Hdim && wc >= 0 && wc < Wdim)
                du += frame[((size_t)hh * Wdim + wc) * Udim + uu] * Dk[t * Udim + uu];
        }
        ys_pdu[((size_t)l * Hdim * Wdim + h * Wdim + w) * Udim + uu] = 2.f * acc[px] + du;
    }
}

// ---------------- group norm stats (per l, group): mean/var over H*W*4 ----------------
__global__ __launch_bounds__(256)
void gnstats_kernel(const float* __restrict__ ys_pdu, float* __restrict__ stats) {
    int g = blockIdx.x;   // 32 groups
    int l = blockIdx.y;   // L
    int tid = threadIdx.x;
    float s = 0.f, s2 = 0.f;
    for (int i = tid; i < Hdim * Wdim * 4; i += 256) {
        int hw = i >> 2;
        int c = i & 3;
        float v = ys_pdu[((size_t)l * Hdim * Wdim + hw) * Udim + g * 4 + c];
        s += v;
        s2 += v * v;
    }
    __shared__ float red[2 * 8];
    for (int off = 32; off > 0; off >>= 1) {
        s += __shfl_down(s, off, 64);
        s2 += __shfl_down(s2, off, 64);
    }
    int wid = tid >> 6;
    if ((tid & 63) == 0) { red[wid] = s; red[8 + wid] = s2; }
    __syncthreads();
    if (tid == 0) {
        float S = 0.f, S2 = 0.f;
        for (int w2 = 0; w2 < 4; ++w2) { S += red[w2]; S2 += red[8 + w2]; }
        const float inv = 1.f / (Hdim * Wdim * 4);
        float mean = S * inv;
        float var = S2 * inv - mean * mean;
        stats[(l * 32 + g) * 2 + 0] = mean;
        stats[(l * 32 + g) * 2 + 1] = var;
    }
}

// ---------------- apply GN + gelu(tanh), write ys output ----------------
__global__ __launch_bounds__(256)
void gnapply_kernel(const float* __restrict__ ys_pdu, const float* __restrict__ stats,
                    const float* __restrict__ scale, const float* __restrict__ bias,
                    float* __restrict__ out_ys, int b) {
    int tid = blockIdx.x * 256 + threadIdx.x;
    const int total = Ldim * Hdim * Wdim * Udim;  // 2,097,152
    if (tid >= total) return;
    int uu = tid % Udim;
    int hw = (tid / Udim) % (Hdim * Wdim);
    int l = tid / (Udim * Hdim * Wdim);
    int g = uu >> 2;
    float mean = stats[(l * 32 + g) * 2 + 0];
    float var = stats[(l * 32 + g) * 2 + 1];
    float v = ys_pdu[tid];
    float xn = (v - mean) * rsqrtf(var + 1e-5f);
    float y = xn * scale[uu] + bias[uu];
    // jax.nn.gelu default: tanh approximation
    const float kAlpha = 0.7978845608028654f;  // sqrt(2/pi)
    float t = kAlpha * (y + 0.044715f * y * y * y);
    float gl = 0.5f * y * (1.f + tanhf(t));
    out_ys[(((size_t)l * BATCH + b) * (Hdim * Wdim) + hw) * Udim + uu] = gl;
}

extern "C" void kernel_launch(void* const* d_in, const int* in_sizes, int n_in,
                              void* d_out, int out_size, void* d_ws, size_t ws_size,
                              hipStream_t stream) {
    const float* useq = (const float*)d_in[0];
    const float* x0 = (const float*)d_in[1];
    const float* Lre = (const float*)d_in[2];
    const float* Lim = (const float*)d_in[3];
    const float* B_ri = (const float*)d_in[4];
    const float* C_ri = (const float*)d_in[5];
    const float* log_step = (const float*)d_in[6];
    const float* Dk = (const float*)d_in[7];
    const float* gsc = (const float*)d_in[8];
    const float* gbi = (const float*)d_in[9];
    float* out = (float*)d_out;
    float* ws = (float*)d_ws;

    float* BusR = ws + OFF_BUSR;
    float* BusI = ws + OFF_BUSI;
    float* ys_pdu = ws + OFF_YS;
    float* stats = ws + OFF_STATS;

    prep_kernel<<<1152, 256, 0, stream>>>(Lre, Lim, B_ri, C_ri, log_step, ws);

    for (int b = 0; b < BATCH; ++b) {
        bconv_kernel<<<dim3(Wdim / 8, Hdim, Ldim), 256, 0, stream>>>(useq, ws, BusR, BusI, b);
        scan_kernel<<<Hdim * Wdim, 256, 0, stream>>>(x0, ws, BusR, BusI, out, b);
        cconv_kernel<<<dim3(Wdim / 4, Hdim, Ldim), 128, 0, stream>>>(useq, ws, BusR, BusI, Dk,
                                                                     ys_pdu, b);
        gnstats_kernel<<<dim3(32, Ldim), 256, 0, stream>>>(ys_pdu, stats);
        gnapply_kernel<<<(Ldim * Hdim * Wdim * Udim + 255) / 256, 256, 0, stream>>>(
            ys_pdu, stats, gsc, gbi, out + 4194304, b);
    }
}

// Round 2
// 1123.837 us; speedup vs baseline: 10.2256x; 10.2256x over previous
//
#include <hip/hip_runtime.h>
#include <hip/hip_bf16.h>
#include <math.h>

#define Ldim 16
#define BATCH 8
#define HWdim 1024
#define Udim 128
#define Pdim 256

typedef __attribute__((ext_vector_type(8))) short s8v;
typedef __attribute__((ext_vector_type(4))) float f32x4;

// workspace byte offsets
#define OFF_WB 0u            // bf16 (9,512,128)   1,179,648 B
#define OFF_WC 1179648u      // bf16 (9,128,512)   1,179,648 B
#define OFF_ABAR 2359296u    // f32 512            2,048 B
#define OFF_STATS 2361344u   // f32 32*32*2        8,192 B
#define OFF_X 2369536u       // bf16 32*1024*512   33,554,432 B
#define OFF_YS 35923968u     // bf16 32*1024*128   8,388,608 B

__device__ __forceinline__ short f2bf(float f) {
    __hip_bfloat16 h = __float2bfloat16(f);
    return __builtin_bit_cast(short, h);
}
__device__ __forceinline__ float bf2f(short s) {
    __hip_bfloat16 h = __builtin_bit_cast(__hip_bfloat16, s);
    return __bfloat162float(h);
}

// ---------------- prep: A_bar + bf16 weight repack ----------------
// Wb[t][c][u]: c<256 -> step[c]*B_ri[c][u][t][re]; c>=256 -> step*B_ri[..][im]
// Wc[t][u][k]: k<256 -> 2*C_ri[u][k][t][re];   k>=256 -> -2*C_ri[u][k-256][t][im]
__global__ __launch_bounds__(256)
void prep_kernel(const float* __restrict__ Lre, const float* __restrict__ Lim,
                 const float* __restrict__ B_ri, const float* __restrict__ C_ri,
                 const float* __restrict__ log_step, short* __restrict__ Wb,
                 short* __restrict__ Wc, float* __restrict__ Abar) {
    int tid = blockIdx.x * 256 + threadIdx.x;
    if (tid < Pdim) {
        float st = expf(log_step[tid]);
        Abar[tid] = fminf(Lre[tid], -1e-4f) * st;
        Abar[Pdim + tid] = Lim[tid] * st;
    }
    const int total = 9 * 512 * 128;
    for (int i = tid; i < total; i += gridDim.x * 256) {
        {   // Wb: i = (t*512 + c)*128 + u
            int u = i & 127;
            int tc = i >> 7;
            int c = tc & 511;
            int t = tc >> 9;
            int p = c & 255;
            int ri = c >> 8;
            float val = B_ri[(((size_t)p * 128 + u) * 9 + t) * 2 + ri] * expf(log_step[p]);
            Wb[i] = f2bf(val);
        }
        {   // Wc: i = (t*128 + u)*512 + k
            int k = i & 511;
            int tu = i >> 9;
            int u = tu & 127;
            int t = tu >> 7;
            int p = k & 255;
            int ri = k >> 8;
            float val = C_ri[(((size_t)u * 256 + p) * 9 + t) * 2 + ri];
            val = ri ? -2.f * val : 2.f * val;
            Wc[i] = f2bf(val);
        }
    }
}

// ---------------- MFMA implicit-GEMM 3x3 SAME conv ----------------
// grid (8 rowgroups, COUT/128 coutgroups, 32 imgs), block 256 = 4 waves (2M x 2N).
// Block tile: 128 pixels (4 image rows x 32 wide) x 128 couts.
// LDS stages 6 halo rows x 34 wide x 128-ch chunk (c-stride 136), reused by all 9 taps.
template <int CIN, int COUT, bool INF32, bool RMW>
__global__ __launch_bounds__(256)
void conv_mfma(const void* __restrict__ inbuf, const short* __restrict__ Wt,
               short* __restrict__ outbuf, int b0) {
    constexpr int NCH = CIN / 128;
    __shared__ short lds[6 * 34 * 136];

    const int tid = threadIdx.x;
    const int lane = tid & 63;
    const int wv = tid >> 6;
    const int waveM = wv & 1, waveN = wv >> 1;
    const int lm = lane & 15, quad = lane >> 4;
    const int h0 = blockIdx.x * 4;
    const int cgp = blockIdx.y;
    const int img = blockIdx.z;
    const int l = img >> 1, bb = b0 + (img & 1);

    int rr[4], ww[4];
#pragma unroll
    for (int mt = 0; mt < 4; ++mt) {
        rr[mt] = waveM * 2 + (mt >> 1);
        ww[mt] = (mt & 1) * 16 + lm;
    }

    f32x4 acc[4][4];
#pragma unroll
    for (int mt = 0; mt < 4; ++mt)
#pragma unroll
        for (int nt = 0; nt < 4; ++nt)
            acc[mt][nt] = (f32x4){0.f, 0.f, 0.f, 0.f};

#pragma unroll 1
    for (int ch = 0; ch < NCH; ++ch) {
        if (ch) __syncthreads();
        // stage 6 rows x 34 x 128ch into LDS (zeros at halo)
        for (int idx = tid; idx < 6 * 34 * 16; idx += 256) {
            int cgi = idx & 15;
            int pos = idx >> 4;
            int w34 = pos % 34;
            int sr = pos / 34;
            int habs = h0 - 1 + sr, wabs = w34 - 1;
            s8v v = {0, 0, 0, 0, 0, 0, 0, 0};
            if ((unsigned)habs < 32u && (unsigned)wabs < 32u) {
                if (INF32) {
                    const float* src = (const float*)inbuf +
                        (((size_t)(l * BATCH + bb) * HWdim + habs * 32 + wabs) * 128 + cgi * 8);
#pragma unroll
                    for (int j = 0; j < 8; ++j) v[j] = f2bf(src[j]);
                } else {
                    v = *(const s8v*)((const short*)inbuf +
                        ((size_t)img * HWdim + habs * 32 + wabs) * (size_t)CIN + ch * 128 + cgi * 8);
                }
            }
            *(s8v*)&lds[(sr * 34 + w34) * 136 + cgi * 8] = v;
        }
        __syncthreads();

#pragma unroll 1
        for (int kh = 0; kh < 3; ++kh) {
#pragma unroll
            for (int kw = 0; kw < 3; ++kw) {
                int t = kh * 3 + kw;
                const short* wbase = Wt +
                    ((size_t)t * COUT + cgp * 128 + waveN * 64 + lm) * CIN + ch * 128 + quad * 8;
#pragma unroll
                for (int ks = 0; ks < 4; ++ks) {
                    s8v a[4], bfr[4];
#pragma unroll
                    for (int mt = 0; mt < 4; ++mt)
                        a[mt] = *(const s8v*)&lds[((rr[mt] + kh) * 34 + (ww[mt] + kw)) * 136 +
                                                  ks * 32 + quad * 8];
#pragma unroll
                    for (int nt = 0; nt < 4; ++nt)
                        bfr[nt] = *(const s8v*)&wbase[(size_t)(nt * 16) * CIN + ks * 32];
#pragma unroll
                    for (int mt = 0; mt < 4; ++mt)
#pragma unroll
                        for (int nt = 0; nt < 4; ++nt)
                            acc[mt][nt] = __builtin_amdgcn_mfma_f32_16x16x32_bf16(
                                a[mt], bfr[nt], acc[mt][nt], 0, 0, 0);
                }
            }
        }
    }

    // epilogue: C/D row = quad*4+reg, col = lm
#pragma unroll
    for (int mt = 0; mt < 4; ++mt) {
#pragma unroll
        for (int reg = 0; reg < 4; ++reg) {
            int mm = waveM * 64 + mt * 16 + quad * 4 + reg;
            int r = mm >> 5, w = mm & 31;
            size_t rowbase = ((size_t)img * HWdim + (h0 + r) * 32 + w) * COUT +
                             cgp * 128 + waveN * 64 + lm;
#pragma unroll
            for (int nt = 0; nt < 4; ++nt) {
                size_t oidx = rowbase + nt * 16;
                float val = acc[mt][nt][reg];
                if (RMW) val += bf2f(outbuf[oidx]);
                outbuf[oidx] = f2bf(val);
            }
        }
    }
}

// ---------------- sequential diagonal scan, in-place on X (bf16), fp32 state ----------------
// grid (1024 hw, 2 b2), block 256 = p
__global__ __launch_bounds__(256)
void scan_kernel(const float* __restrict__ x0, const float* __restrict__ Abar,
                 short* __restrict__ X, float* __restrict__ out_xlast, int b0) {
    int p = threadIdx.x;
    int hw = blockIdx.x;
    int b2 = blockIdx.y;
    int b = b0 + b2;
    float Ar = Abar[p], Ai = Abar[Pdim + p];
    float xr = x0[((size_t)b * HWdim + hw) * Pdim + p];
    float xi = 0.f;
    for (int l = 0; l < Ldim; ++l) {
        size_t base = ((size_t)(l * 2 + b2) * HWdim + hw) * 512 + p;
        float br = bf2f(X[base]), bi = bf2f(X[base + 256]);
        float nr = Ar * xr - Ai * xi + br;
        float ni = Ar * xi + Ai * xr + bi;
        xr = nr; xi = ni;
        X[base] = f2bf(xr);
        X[base + 256] = f2bf(xi);
    }
    size_t o = ((size_t)b * HWdim + hw) * Pdim + p;
    out_xlast[o * 2 + 0] = xr;
    out_xlast[o * 2 + 1] = xi;
}

// ---------------- depthwise D conv -> ys (bf16) ----------------
__global__ __launch_bounds__(256)
void du_kernel(const float* __restrict__ u, const float* __restrict__ Dk,
               short* __restrict__ ys, int b0) {
    int tid = blockIdx.x * 256 + threadIdx.x;  // over 32*1024*128
    int uu = tid & 127;
    int hw = (tid >> 7) & 1023;
    int img = tid >> 17;
    int h = hw >> 5, w = hw & 31;
    int l = img >> 1, b = b0 + (img & 1);
    const float* frame = u + (size_t)(l * BATCH + b) * HWdim * 128;
    float s = 0.f;
#pragma unroll
    for (int kh = 0; kh < 3; ++kh)
#pragma unroll
        for (int kw = 0; kw < 3; ++kw) {
            int hh = h + kh - 1, wc = w + kw - 1;
            if ((unsigned)hh < 32u && (unsigned)wc < 32u)
                s += frame[((size_t)hh * 32 + wc) * 128 + uu] * Dk[(kh * 3 + kw) * 128 + uu];
        }
    ys[tid] = f2bf(s);
}

// ---------------- group norm stats over (hw, 4ch) per (img, group) ----------------
__global__ __launch_bounds__(256)
void gnstats_kernel(const short* __restrict__ ys, float* __restrict__ stats) {
    int g = blockIdx.x;
    int img = blockIdx.y;
    int tid = threadIdx.x;
    float s = 0.f, s2 = 0.f;
    for (int i = tid; i < HWdim * 4; i += 256) {
        int hw = i >> 2;
        int c = i & 3;
        float v = bf2f(ys[((size_t)img * HWdim + hw) * 128 + g * 4 + c]);
        s += v;
        s2 += v * v;
    }
    __shared__ float red[16];
    for (int off = 32; off > 0; off >>= 1) {
        s += __shfl_down(s, off, 64);
        s2 += __shfl_down(s2, off, 64);
    }
    int wid = tid >> 6;
    if ((tid & 63) == 0) { red[wid] = s; red[8 + wid] = s2; }
    __syncthreads();
    if (tid == 0) {
        float S = 0.f, S2 = 0.f;
        for (int w2 = 0; w2 < 4; ++w2) { S += red[w2]; S2 += red[8 + w2]; }
        const float inv = 1.f / (HWdim * 4);
        float mean = S * inv;
        float var = S2 * inv - mean * mean;
        stats[(img * 32 + g) * 2 + 0] = mean;
        stats[(img * 32 + g) * 2 + 1] = var;
    }
}

// ---------------- apply GN + gelu(tanh) ----------------
__global__ __launch_bounds__(256)
void gnapply_kernel(const short* __restrict__ ys, const float* __restrict__ stats,
                    const float* __restrict__ scale, const float* __restrict__ bias,
                    float* __restrict__ out_ys, int b0) {
    int tid = blockIdx.x * 256 + threadIdx.x;  // over 32*1024*128
    int uu = tid & 127;
    int hw = (tid >> 7) & 1023;
    int img = tid >> 17;
    int l = img >> 1, b = b0 + (img & 1);
    int g = uu >> 2;
    float mean = stats[(img * 32 + g) * 2 + 0];
    float var = stats[(img * 32 + g) * 2 + 1];
    float v = bf2f(ys[tid]);
    float xn = (v - mean) * rsqrtf(var + 1e-5f);
    float y = xn * scale[uu] + bias[uu];
    const float kAlpha = 0.7978845608028654f;
    float t = kAlpha * (y + 0.044715f * y * y * y);
    float gl = 0.5f * y * (1.f + tanhf(t));
    out_ys[((size_t)(l * BATCH + b) * HWdim + hw) * 128 + uu] = gl;
}

extern "C" void kernel_launch(void* const* d_in, const int* in_sizes, int n_in,
                              void* d_out, int out_size, void* d_ws, size_t ws_size,
                              hipStream_t stream) {
    const float* useq = (const float*)d_in[0];
    const float* x0 = (const float*)d_in[1];
    const float* Lre = (const float*)d_in[2];
    const float* Lim = (const float*)d_in[3];
    const float* B_ri = (const float*)d_in[4];
    const float* C_ri = (const float*)d_in[5];
    const float* log_step = (const float*)d_in[6];
    const float* Dk = (const float*)d_in[7];
    const float* gsc = (const float*)d_in[8];
    const float* gbi = (const float*)d_in[9];
    float* out = (float*)d_out;

    char* wsb = (char*)d_ws;
    short* Wb = (short*)(wsb + OFF_WB);
    short* Wc = (short*)(wsb + OFF_WC);
    float* Abar = (float*)(wsb + OFF_ABAR);
    float* stats = (float*)(wsb + OFF_STATS);
    short* X = (short*)(wsb + OFF_X);
    short* YS = (short*)(wsb + OFF_YS);

    prep_kernel<<<2304, 256, 0, stream>>>(Lre, Lim, B_ri, C_ri, log_step, Wb, Wc, Abar);

    for (int g = 0; g < 4; ++g) {
        int b0 = g * 2;
        // B conv: u (fp32, 128ch) -> X (bf16, 512ch = [BusR, BusI])
        conv_mfma<128, 512, true, false><<<dim3(8, 4, 32), 256, 0, stream>>>(useq, Wb, X, b0);
        // scan over L in place, emits x_last fp32
        scan_kernel<<<dim3(HWdim, 2), 256, 0, stream>>>(x0, Abar, X, out, b0);
        // depthwise feedthrough into ys
        du_kernel<<<16384, 256, 0, stream>>>(useq, Dk, YS, b0);
        // C conv: X (bf16, 512ch) -> ys += 2*Re(C conv x)  (RMW)
        conv_mfma<512, 128, false, true><<<dim3(8, 1, 32), 256, 0, stream>>>(X, Wc, YS, b0);
        gnstats_kernel<<<dim3(32, 32), 256, 0, stream>>>(YS, stats);
        gnapply_kernel<<<16384, 256, 0, stream>>>(YS, stats, gsc, gbi, out + 4194304, b0);
    }
}

// Round 3
// 878.490 us; speedup vs baseline: 13.0814x; 1.2793x over previous
//
#include <hip/hip_runtime.h>
#include <hip/hip_bf16.h>
#include <math.h>

#define Ldim 16
#define BATCH 8
#define HWdim 1024

typedef __attribute__((ext_vector_type(8))) short s8v;
typedef __attribute__((ext_vector_type(4))) short s4v;
typedef __attribute__((ext_vector_type(2))) short s2v;
typedef __attribute__((ext_vector_type(4))) float f32x4;
typedef __attribute__((ext_vector_type(2))) float f32x2;

__device__ __forceinline__ short f2bf(float f) {
    __hip_bfloat16 h = __float2bfloat16(f);
    return __builtin_bit_cast(short, h);
}
__device__ __forceinline__ float bf2f(short s) {
    __hip_bfloat16 h = __builtin_bit_cast(__hip_bfloat16, s);
    return __bfloat162float(h);
}

// ---------------- prep: A_bar + bf16 weight repack ----------------
// X channel layout: ch = 2p+ri (re/im interleaved per state p).
// Wb[t][cout][u], cout = 2p+ri : step[p] * B_ri[p][u][t][ri]
// Wc[t][u][k],   k   = 2p+ri : (ri? -2 : 2) * C_ri[u][p][t][ri]
__global__ __launch_bounds__(256)
void prep_kernel(const float* __restrict__ Lre, const float* __restrict__ Lim,
                 const float* __restrict__ B_ri, const float* __restrict__ C_ri,
                 const float* __restrict__ log_step, short* __restrict__ Wb,
                 short* __restrict__ Wc, float* __restrict__ Abar) {
    int tid = blockIdx.x * 256 + threadIdx.x;
    if (tid < 256) {
        float st = expf(log_step[tid]);
        Abar[tid] = fminf(Lre[tid], -1e-4f) * st;
        Abar[256 + tid] = Lim[tid] * st;
    }
    const int total = 9 * 512 * 128;
    for (int i = tid; i < total; i += gridDim.x * 256) {
        {   // Wb: i = (t*512 + cout)*128 + u
            int u = i & 127;
            int tc = i >> 7;
            int cout = tc & 511;
            int t = tc >> 9;
            int p = cout >> 1, ri = cout & 1;
            float val = B_ri[(((size_t)p * 128 + u) * 9 + t) * 2 + ri] * expf(log_step[p]);
            Wb[i] = f2bf(val);
        }
        {   // Wc: i = (t*128 + u)*512 + k
            int k = i & 511;
            int tu = i >> 9;
            int uu = tu & 127;
            int t = tu >> 7;
            int p = k >> 1, ri = k & 1;
            float val = C_ri[(((size_t)uu * 256 + p) * 9 + t) * 2 + ri];
            val = ri ? -2.f * val : 2.f * val;
            Wc[i] = f2bf(val);
        }
    }
}

// ---------------- u -> bf16 once for all (L,B) ----------------
__global__ __launch_bounds__(256)
void ubf_kernel(const float* __restrict__ u, short* __restrict__ Ubf) {
    size_t t8 = ((size_t)blockIdx.x * 256 + threadIdx.x) * 8;
    f32x4 v0 = *(const f32x4*)(u + t8);
    f32x4 v1 = *(const f32x4*)(u + t8 + 4);
    s8v o;
#pragma unroll
    for (int j = 0; j < 4; ++j) { o[j] = f2bf(v0[j]); o[4 + j] = f2bf(v1[j]); }
    *(s8v*)(Ubf + t8) = o;
}

// ---------------- MFMA implicit-GEMM 3x3 SAME conv ----------------
// grid (8 rowgroups, COUT/128, 16*G imgs), block 256 = 4 waves (2M x 2N).
// Block tile: 128 pixels (4 rows x 32) x 128 couts. LDS stages 6x34 halo patch
// for 64-ch chunks, 16B-chunk XOR-swizzled (chunk ^ pixel&7) -> conflict-free.
template <int CIN, int COUT, bool INF32, bool INFULL, bool RMW>
__global__ __launch_bounds__(256)
void conv_mfma(const void* __restrict__ inbuf, const short* __restrict__ Wt,
               short* __restrict__ outbuf, int b0, int Gshift) {
    constexpr int NCH = CIN / 64;
    __shared__ short lds[6 * 34 * 64];  // 26,112 B

    const int tid = threadIdx.x;
    const int lane = tid & 63;
    const int wv = tid >> 6;
    const int waveM = wv & 1, waveN = wv >> 1;
    const int lm = lane & 15, quad = lane >> 4;
    const int h0 = blockIdx.x * 4;
    const int cgp = blockIdx.y;
    const int img = blockIdx.z;
    const int l = img >> Gshift;
    const int bi = img & ((1 << Gshift) - 1);
    const size_t inframe = INFULL ? (size_t)(l * BATCH + b0 + bi) : (size_t)img;

    f32x4 acc[4][4];
#pragma unroll
    for (int mt = 0; mt < 4; ++mt)
#pragma unroll
        for (int nt = 0; nt < 4; ++nt)
            acc[mt][nt] = (f32x4){0.f, 0.f, 0.f, 0.f};

#pragma unroll 1
    for (int ch = 0; ch < NCH; ++ch) {
        if (ch) __syncthreads();
        for (int idx = tid; idx < 6 * 34 * 8; idx += 256) {
            int cgi = idx & 7;
            int pos = idx >> 3;
            int w34 = pos % 34;
            int sr = pos / 34;
            int habs = h0 - 1 + sr, wabs = w34 - 1;
            s8v v = {0, 0, 0, 0, 0, 0, 0, 0};
            if ((unsigned)habs < 32u && (unsigned)wabs < 32u) {
                size_t off = (inframe * HWdim + habs * 32 + wabs) * (size_t)CIN + ch * 64 + cgi * 8;
                if (INF32) {
                    const float* src = (const float*)inbuf + off;
                    f32x4 a0 = *(const f32x4*)src;
                    f32x4 a1 = *(const f32x4*)(src + 4);
#pragma unroll
                    for (int j = 0; j < 4; ++j) { v[j] = f2bf(a0[j]); v[4 + j] = f2bf(a1[j]); }
                } else {
                    v = *(const s8v*)((const short*)inbuf + off);
                }
            }
            *(s8v*)&lds[(((pos << 3) + (cgi ^ (pos & 7))) << 3)] = v;
        }
        __syncthreads();

#pragma unroll 1
        for (int kh = 0; kh < 3; ++kh) {
#pragma unroll
            for (int kw = 0; kw < 3; ++kw) {
                int t = kh * 3 + kw;
                const short* wbase = Wt +
                    ((size_t)t * COUT + cgp * 128 + waveN * 64 + lm) * CIN + ch * 64 + quad * 8;
#pragma unroll
                for (int ks = 0; ks < 2; ++ks) {
                    s8v a[4], bfr[4];
#pragma unroll
                    for (int mt = 0; mt < 4; ++mt) {
                        int p = (waveM * 2 + (mt >> 1) + kh) * 34 + (mt & 1) * 16 + lm + kw;
                        int c = ks * 4 + quad;
                        a[mt] = *(const s8v*)&lds[(((p << 3) + (c ^ (p & 7))) << 3)];
                    }
#pragma unroll
                    for (int nt = 0; nt < 4; ++nt)
                        bfr[nt] = *(const s8v*)&wbase[(size_t)(nt * 16) * CIN + ks * 32];
#pragma unroll
                    for (int mt = 0; mt < 4; ++mt)
#pragma unroll
                        for (int nt = 0; nt < 4; ++nt)
                            acc[mt][nt] = __builtin_amdgcn_mfma_f32_16x16x32_bf16(
                                a[mt], bfr[nt], acc[mt][nt], 0, 0, 0);
                }
            }
        }
    }

    // epilogue: C/D row(m)=quad*4+reg (pixel), col(n)=lm (cout)
#pragma unroll
    for (int mt = 0; mt < 4; ++mt) {
#pragma unroll
        for (int reg = 0; reg < 4; ++reg) {
            int mm = waveM * 64 + mt * 16 + quad * 4 + reg;
            int r = mm >> 5, w = mm & 31;
            size_t rowbase = ((size_t)img * HWdim + (h0 + r) * 32 + w) * COUT +
                             cgp * 128 + waveN * 64 + lm;
#pragma unroll
            for (int nt = 0; nt < 4; ++nt) {
                size_t oidx = rowbase + nt * 16;
                float val = acc[mt][nt][reg];
                if (RMW) val += bf2f(outbuf[oidx]);
                outbuf[oidx] = f2bf(val);
            }
        }
    }
}

// ---------------- sequential diagonal scan, in-place on X, fp32 state ----------------
__global__ __launch_bounds__(256)
void scan_kernel(const float* __restrict__ x0, const float* __restrict__ Abar,
                 short* __restrict__ X, float* __restrict__ out_xlast, int b0, int G) {
    int p = threadIdx.x;
    int hw = blockIdx.x;
    int bi = blockIdx.y;
    int b = b0 + bi;
    float Ar = Abar[p], Ai = Abar[256 + p];
    float xr = x0[((size_t)b * HWdim + hw) * 256 + p];
    float xi = 0.f;
    for (int l = 0; l < Ldim; ++l) {
        size_t base = ((size_t)(l * G + bi) * HWdim + hw) * 512 + p * 2;
        s2v v = *(s2v*)&X[base];
        float br = bf2f(v[0]), bim = bf2f(v[1]);
        float nr = Ar * xr - Ai * xi + br;
        float ni = Ar * xi + Ai * xr + bim;
        xr = nr; xi = ni;
        v[0] = f2bf(xr); v[1] = f2bf(xi);
        *(s2v*)&X[base] = v;
    }
    f32x2 o2 = {xr, xi};
    *(f32x2*)&out_xlast[(((size_t)b * HWdim + hw) * 256 + p) * 2] = o2;
}

// ---------------- depthwise D conv -> ys (bf16), 4 ch/thread ----------------
template <bool UBF>
__global__ __launch_bounds__(256)
void du_kernel(const void* __restrict__ uin, const float* __restrict__ Dk,
               short* __restrict__ ys, int b0, int Gshift) {
    int tid = blockIdx.x * 256 + threadIdx.x;  // imgs*1024*32
    int c4 = tid & 31;
    int hw = (tid >> 5) & 1023;
    int img = tid >> 15;
    int h = hw >> 5, w = hw & 31;
    int l = img >> Gshift, bi = img & ((1 << Gshift) - 1);
    size_t fbase = ((size_t)(l * BATCH + b0 + bi)) * HWdim * 128;
    float s0 = 0.f, s1 = 0.f, s2 = 0.f, s3 = 0.f;
#pragma unroll
    for (int kh = 0; kh < 3; ++kh)
#pragma unroll
        for (int kw = 0; kw < 3; ++kw) {
            int hh = h + kh - 1, wc = w + kw - 1;
            if ((unsigned)hh < 32u && (unsigned)wc < 32u) {
                f32x4 d = *(const f32x4*)&Dk[(kh * 3 + kw) * 128 + c4 * 4];
                size_t off = fbase + ((size_t)hh * 32 + wc) * 128 + c4 * 4;
                if (UBF) {
                    s4v v = *(const s4v*)((const short*)uin + off);
                    s0 += bf2f(v[0]) * d[0]; s1 += bf2f(v[1]) * d[1];
                    s2 += bf2f(v[2]) * d[2]; s3 += bf2f(v[3]) * d[3];
                } else {
                    f32x4 v = *(const f32x4*)((const float*)uin + off);
                    s0 += v[0] * d[0]; s1 += v[1] * d[1];
                    s2 += v[2] * d[2]; s3 += v[3] * d[3];
                }
            }
        }
    s4v o = {f2bf(s0), f2bf(s1), f2bf(s2), f2bf(s3)};
    *(s4v*)&ys[(size_t)tid * 4] = o;
}

// ---------------- group norm stats per (img, group) ----------------
__global__ __launch_bounds__(256)
void gnstats_kernel(const short* __restrict__ ys, float* __restrict__ stats) {
    int g = blockIdx.x;
    int img = blockIdx.y;
    int tid = threadIdx.x;
    float s = 0.f, s2 = 0.f;
    for (int hw = tid; hw < HWdim; hw += 256) {
        s4v v = *(const s4v*)&ys[((size_t)img * HWdim + hw) * 128 + g * 4];
#pragma unroll
        for (int j = 0; j < 4; ++j) {
            float f = bf2f(v[j]);
            s += f; s2 += f * f;
        }
    }
    __shared__ float red[16];
    for (int off = 32; off > 0; off >>= 1) {
        s += __shfl_down(s, off, 64);
        s2 += __shfl_down(s2, off, 64);
    }
    int wid = tid >> 6;
    if ((tid & 63) == 0) { red[wid] = s; red[8 + wid] = s2; }
    __syncthreads();
    if (tid == 0) {
        float S = 0.f, S2 = 0.f;
        for (int w2 = 0; w2 < 4; ++w2) { S += red[w2]; S2 += red[8 + w2]; }
        const float inv = 1.f / (HWdim * 4);
        float mean = S * inv;
        float var = S2 * inv - mean * mean;
        stats[(img * 32 + g) * 2 + 0] = mean;
        stats[(img * 32 + g) * 2 + 1] = var;
    }
}

// ---------------- apply GN + gelu(tanh), 4 ch/thread ----------------
__global__ __launch_bounds__(256)
void gnapply_kernel(const short* __restrict__ ys, const float* __restrict__ stats,
                    const float* __restrict__ scale, const float* __restrict__ bias,
                    float* __restrict__ out_ys, int b0, int Gshift) {
    int tid = blockIdx.x * 256 + threadIdx.x;  // imgs*1024*32
    int c4 = tid & 31;
    int hw = (tid >> 5) & 1023;
    int img = tid >> 15;
    int l = img >> Gshift, bi = img & ((1 << Gshift) - 1);
    float mean = stats[(img * 32 + c4) * 2 + 0];
    float var = stats[(img * 32 + c4) * 2 + 1];
    float rstd = rsqrtf(var + 1e-5f);
    s4v v = *(const s4v*)&ys[(size_t)tid * 4];
    f32x4 sc = *(const f32x4*)&scale[c4 * 4];
    f32x4 bs = *(const f32x4*)&bias[c4 * 4];
    f32x4 o;
    const float kAlpha = 0.7978845608028654f;
#pragma unroll
    for (int j = 0; j < 4; ++j) {
        float y = (bf2f(v[j]) - mean) * rstd * sc[j] + bs[j];
        float t = kAlpha * (y + 0.044715f * y * y * y);
        o[j] = 0.5f * y * (1.f + tanhf(t));
    }
    *(f32x4*)&out_ys[(((size_t)(l * BATCH + b0 + bi)) * HWdim + hw) * 128 + c4 * 4] = o;
}

extern "C" void kernel_launch(void* const* d_in, const int* in_sizes, int n_in,
                              void* d_out, int out_size, void* d_ws, size_t ws_size,
                              hipStream_t stream) {
    const float* useq = (const float*)d_in[0];
    const float* x0 = (const float*)d_in[1];
    const float* Lre = (const float*)d_in[2];
    const float* Lim = (const float*)d_in[3];
    const float* B_ri = (const float*)d_in[4];
    const float* C_ri = (const float*)d_in[5];
    const float* log_step = (const float*)d_in[6];
    const float* Dk = (const float*)d_in[7];
    const float* gsc = (const float*)d_in[8];
    const float* gbi = (const float*)d_in[9];
    float* out = (float*)d_out;

    const size_t WBYTES = 9 * 512 * 128 * 2;       // 1,179,648
    const size_t UBF_BYTES = (size_t)Ldim * BATCH * HWdim * 128 * 2;  // 33,554,432

    // choose batch group G and whether to pre-convert u to bf16
    int G = 2;
    bool ubf = false;
    {
        auto need = [&](int g, bool u) -> size_t {
            size_t base = 2 * WBYTES + 2048 + (size_t)g * 4096;
            size_t x = (size_t)g * Ldim * HWdim * 512 * 2;
            size_t ysb = (size_t)g * Ldim * HWdim * 128 * 2;
            return base + x + ysb + (u ? UBF_BYTES : 0);
        };
        if (ws_size >= need(8, true)) { G = 8; ubf = true; }
        else if (ws_size >= need(8, false)) { G = 8; }
        else if (ws_size >= need(4, true)) { G = 4; ubf = true; }
        else if (ws_size >= need(4, false)) { G = 4; }
        else if (ws_size >= need(2, true)) { G = 2; ubf = true; }
    }
    int Gshift = (G == 8) ? 3 : (G == 4) ? 2 : 1;
    int imgs = Ldim * G;

    char* wsb = (char*)d_ws;
    short* Wb = (short*)(wsb);
    short* Wc = (short*)(wsb + WBYTES);
    float* Abar = (float*)(wsb + 2 * WBYTES);
    float* stats = (float*)(wsb + 2 * WBYTES + 2048);
    size_t offX = 2 * WBYTES + 2048 + (size_t)G * 4096;
    short* X = (short*)(wsb + offX);
    size_t offYS = offX + (size_t)G * Ldim * HWdim * 512 * 2;
    short* YS = (short*)(wsb + offYS);
    short* Ubf = (short*)(wsb + offYS + (size_t)G * Ldim * HWdim * 128 * 2);

    prep_kernel<<<2304, 256, 0, stream>>>(Lre, Lim, B_ri, C_ri, log_step, Wb, Wc, Abar);
    if (ubf) ubf_kernel<<<8192, 256, 0, stream>>>(useq, Ubf);

    for (int b0 = 0; b0 < BATCH; b0 += G) {
        // B conv: u (128ch) -> X (bf16, 512ch interleaved re/im)
        if (ubf)
            conv_mfma<128, 512, false, true, false><<<dim3(8, 4, imgs), 256, 0, stream>>>(
                Ubf, Wb, X, b0, Gshift);
        else
            conv_mfma<128, 512, true, true, false><<<dim3(8, 4, imgs), 256, 0, stream>>>(
                useq, Wb, X, b0, Gshift);
        // scan over L in place, emits x_last fp32
        scan_kernel<<<dim3(HWdim, G), 256, 0, stream>>>(x0, Abar, X, out, b0, G);
        // depthwise feedthrough into ys
        if (ubf)
            du_kernel<true><<<imgs * 128, 256, 0, stream>>>(Ubf, Dk, YS, b0, Gshift);
        else
            du_kernel<false><<<imgs * 128, 256, 0, stream>>>(useq, Dk, YS, b0, Gshift);
        // C conv: X (512ch) -> ys += 2*Re(C conv x)  (RMW)
        conv_mfma<512, 128, false, false, true><<<dim3(8, 1, imgs), 256, 0, stream>>>(
            X, Wc, YS, b0, Gshift);
        gnstats_kernel<<<dim3(32, imgs), 256, 0, stream>>>(YS, stats);
        gnapply_kernel<<<imgs * 128, 256, 0, stream>>>(YS, stats, gsc, gbi, out + 4194304, b0,
                                                       Gshift);
    }
}